// Round 14
// baseline (561.234 us; speedup 1.0000x reference)
//
#include <hip/hip_runtime.h>
#include <hip/hip_bf16.h>

typedef __attribute__((ext_vector_type(8))) short short8;
typedef __attribute__((ext_vector_type(4))) short short4v;
typedef __attribute__((ext_vector_type(4))) float floatx4;
typedef __attribute__((ext_vector_type(16))) float floatx16;
typedef __attribute__((ext_vector_type(4))) unsigned int uintx4;

__device__ __forceinline__ float b2f(ushort u) {
  unsigned x = ((unsigned)u) << 16;
  return __builtin_bit_cast(float, x);
}
__device__ __forceinline__ ushort f2b(float f) {
  unsigned x = __builtin_bit_cast(unsigned, f);
  x += 0x7fffu + ((x >> 16) & 1u);
  return (ushort)(x >> 16);
}

__device__ __forceinline__ void gload_lds16(const void* g, void* l) {
  __builtin_amdgcn_global_load_lds(
      (const __attribute__((address_space(1))) unsigned int*)g,
      (__attribute__((address_space(3))) unsigned int*)l, 16, 0, 0);
}

// P-fragment build (T12): cvt_pk + permlane32_swap (direction verified r10/r11).
__device__ __forceinline__ short8 mkpa8(float p0, float p1, float p2, float p3,
                                        float p4, float p5, float p6, float p7) {
  unsigned a0, a1, b0, b1;
  asm("v_cvt_pk_bf16_f32 %0, %1, %2" : "=v"(a0) : "v"(p0), "v"(p1));
  asm("v_cvt_pk_bf16_f32 %0, %1, %2" : "=v"(a1) : "v"(p2), "v"(p3));
  asm("v_cvt_pk_bf16_f32 %0, %1, %2" : "=v"(b0) : "v"(p4), "v"(p5));
  asm("v_cvt_pk_bf16_f32 %0, %1, %2" : "=v"(b1) : "v"(p6), "v"(p7));
  asm volatile("v_permlane32_swap_b32 %0, %1" : "+v"(a0), "+v"(b0));
  asm volatile("v_permlane32_swap_b32 %0, %1" : "+v"(a1), "+v"(b1));
  uintx4 u;
  u[0] = a0;  // kv 0,1 (lo) / 8,9  (hi)
  u[1] = a1;  // kv 2,3 (lo) / 10,11(hi)
  u[2] = b0;  // kv 4,5 (lo) / 12,13(hi)
  u[3] = b1;  // kv 6,7 (lo) / 14,15(hi)
  return __builtin_bit_cast(short8, u);
}

// ---------------- f32 -> bf16 conversion ----------------
__global__ __launch_bounds__(256) void cvt_kernel(const float* __restrict__ in,
                                                  ushort* __restrict__ out, long n) {
  long i0 = ((long)blockIdx.x * 256 + threadIdx.x) * 4;
  long stride = (long)gridDim.x * 256 * 4;
  for (long i = i0; i < n; i += stride) {
    float4 v = *(const float4*)(in + i);
    ushort4 u;
    u.x = f2b(v.x); u.y = f2b(v.y); u.z = f2b(v.z); u.w = f2b(v.w);
    *(ushort4*)(out + i) = u;
  }
}

// ---------------- pipelined 256xBN GEMM: C[M,N] = A[M,K] * B[N,K]^T ----------------
// r5 structure (proven 186/92 us). Do not re-tinker the wait structure.
template <int BN, int OUTBF16>
__global__ __launch_bounds__(512, 2)
void gemm_pipe(const ushort* __restrict__ A, const ushort* __restrict__ B,
               float* __restrict__ Cf, ushort* __restrict__ Cb,
               int M, int N, int K) {
  constexpr int BNF = BN / 64;
  __shared__ __align__(16) ushort sA[2][256 * 64];
  __shared__ __align__(16) ushort sB[2][BN * 64];
  const int t = threadIdx.x;
  const int lane = t & 63;
  const int L = lane & 15, g = lane >> 4;
  const int w = t >> 6;
  const int wr = w >> 2, wc = w & 3;
  const int ntn = N / BN;
  const int nwg = gridDim.x;
  const int wg = blockIdx.x;
  const int swz = (wg & 7) * (nwg >> 3) + (wg >> 3);
  const int m0 = (swz / ntn) << 8;
  const int n0 = (swz % ntn) * BN;

  floatx4 acc[8][BNF];
#pragma unroll
  for (int i = 0; i < 8; i++)
#pragma unroll
    for (int j = 0; j < BNF; j++) acc[i][j] = (floatx4)(0.0f);

  const ushort* Ab = A + (size_t)m0 * K;
  const ushort* Bb = B + (size_t)n0 * K;

  auto stage_tile = [&](const ushort* Ag, const ushort* Bg, int buf) {
#pragma unroll
    for (int j = 0; j < 4; j++) {
      const int c = j * 512 + t;
      const int row = c >> 3, ch = c & 7;
      const int kc = ch ^ (row & 7);
      gload_lds16(Ag + (size_t)row * K + kc * 8, (char*)&sA[buf][0] + c * 16);
    }
#pragma unroll
    for (int j = 0; j < BN / 64; j++) {
      const int c = j * 512 + t;
      const int row = c >> 3, ch = c & 7;
      const int kc = ch ^ (row & 7);
      gload_lds16(Bg + (size_t)row * K + kc * 8, (char*)&sB[buf][0] + c * 16);
    }
  };
  auto rdA = [&](int buf, int mh, int kc16, short8* dst) {
#pragma unroll
    for (int i = 0; i < 4; i++) {
      const int row = wr * 128 + mh * 64 + i * 16 + L;
      const int ch = (kc16 * 4 + g) ^ (row & 7);
      dst[i] = *(const short8*)((const char*)&sA[buf][0] + row * 128 + ch * 16);
    }
  };
  auto rdB = [&](int buf, int kc16, short8* dst) {
#pragma unroll
    for (int i = 0; i < BNF; i++) {
      const int row = wc * (BN / 4) + i * 16 + L;
      const int ch = (kc16 * 4 + g) ^ (row & 7);
      dst[i] = *(const short8*)((const char*)&sB[buf][0] + row * 128 + ch * 16);
    }
  };

  short8 a0[4], a1[4], b0[BNF], b1[BNF];

  auto mfmaN = [&](short8* af, short8* bf, int accbase, int cnt) {
    __builtin_amdgcn_s_setprio(1);
    for (int i = 0; i < cnt; i++)
#pragma unroll
      for (int nf = 0; nf < BNF; nf++)
        acc[accbase + i][nf] =
            __builtin_amdgcn_mfma_f32_16x16x32_bf16(af[i], bf[nf], acc[accbase + i][nf], 0, 0, 0);
    __builtin_amdgcn_s_setprio(0);
  };

  const int NT = K >> 6;
  stage_tile(Ab, Bb, 0);
  __syncthreads();
  rdA(0, 0, 0, a0);
  rdB(0, 0, b0);

  for (int T = 0; T < NT; ++T) {
    const int p = T & 1, q = p ^ 1;
    const bool more = (T + 1 < NT);
    if (more) stage_tile(Ab + (T + 1) * 64, Bb + (T + 1) * 64, q);
    rdA(p, 1, 0, a1);
    mfmaN(a0, b0, 0, 4);
    rdA(p, 0, 1, a0);
    rdB(p, 1, b1);
    mfmaN(a1, b0, 4, 4);
    rdA(p, 1, 1, a1);
    mfmaN(a0, b1, 0, 4);
    mfmaN(a1, b1, 4, 2);
    __syncthreads();
    if (more) {
      rdA(q, 0, 0, a0);
      rdB(q, 0, b0);
    }
    mfmaN(a1 + 2, b1, 6, 2);
  }

#pragma unroll
  for (int mf = 0; mf < 8; mf++)
#pragma unroll
    for (int nf = 0; nf < BNF; nf++)
#pragma unroll
      for (int r = 0; r < 4; r++) {
        const int row = m0 + wr * 128 + mf * 16 + g * 4 + r;
        const int col = n0 + wc * (BN / 4) + nf * 16 + L;
        if (OUTBF16)
          Cb[(size_t)row * N + col] = f2b(acc[mf][nf][r]);
        else
          Cf[(size_t)row * N + col] = acc[mf][nf][r];
      }
}

// ---------------- RoPE + split qkv -> Q[B,H,T,D], K[B,HK,T,D] ----------------
__global__ __launch_bounds__(256)
void rope_kernel(const ushort* __restrict__ qkv, const float* __restrict__ cosp,
                 const float* __restrict__ sinp, ushort* __restrict__ Qo,
                 ushort* __restrict__ Ko) {
  const int row = blockIdx.x;            // b*2048 + t
  const int b = row >> 11, tt = row & 2047;
  const int i = threadIdx.x;
  const ushort* qr = qkv + (size_t)row * 6144;

  const int jb = (i & 7) * 8;
  float cs[8], sn[8];
  *(float4*)&cs[0] = *(const float4*)(cosp + tt * 128 + jb);
  *(float4*)&cs[4] = *(const float4*)(cosp + tt * 128 + jb + 4);
  *(float4*)&sn[0] = *(const float4*)(sinp + tt * 128 + jb);
  *(float4*)&sn[4] = *(const float4*)(sinp + tt * 128 + jb + 4);

  {
    const int hh = i >> 3;
    short8 lo = *(const short8*)(qr + hh * 128 + jb);
    short8 hi = *(const short8*)(qr + hh * 128 + 64 + jb);
    short8 olo, ohi;
#pragma unroll
    for (int e = 0; e < 8; e++) {
      float fl = b2f((ushort)lo[e]), fh = b2f((ushort)hi[e]);
      olo[e] = (short)f2b(fl * cs[e] - fh * sn[e]);
      ohi[e] = (short)f2b(fh * cs[e] + fl * sn[e]);
    }
    ushort* dst = Qo + ((size_t)(b * 32 + hh) * 2048 + tt) * 128 + jb;
    *(short8*)dst = olo;
    *(short8*)(dst + 64) = ohi;
  }
  if (i < 64) {
    const int hkk = i >> 3;
    short8 lo = *(const short8*)(qr + 4096 + hkk * 128 + jb);
    short8 hi = *(const short8*)(qr + 4096 + hkk * 128 + 64 + jb);
    short8 olo, ohi;
#pragma unroll
    for (int e = 0; e < 8; e++) {
      float fl = b2f((ushort)lo[e]), fh = b2f((ushort)hi[e]);
      olo[e] = (short)f2b(fl * cs[e] - fh * sn[e]);
      ohi[e] = (short)f2b(fh * cs[e] + fl * sn[e]);
    }
    ushort* dst = Ko + ((size_t)(b * 8 + hkk) * 2048 + tt) * 128 + jb;
    *(short8*)dst = olo;
    *(short8*)(dst + 64) = ohi;
  }
}

// ---------------- V transpose: qkv V slice -> Vt[B,HK,D,T] ----------------
__global__ __launch_bounds__(256)
void vtrans_kernel(const ushort* __restrict__ qkv, ushort* __restrict__ Vt) {
  const int bx = blockIdx.x;
  const int t0 = (bx & 31) * 64;
  const int hk = (bx >> 5) & 7;
  const int b = bx >> 8;
  const int i = threadIdx.x;
  const int tq = i & 15;
  const int dn = i >> 4;
  const ushort* src = qkv + ((size_t)(b * 2048 + t0 + tq * 4)) * 6144 + 5120 + hk * 128 + dn * 8;
  short8 v0 = *(const short8*)(src);
  short8 v1 = *(const short8*)(src + 6144);
  short8 v2 = *(const short8*)(src + 12288);
  short8 v3 = *(const short8*)(src + 18432);
  ushort* dst = Vt + ((size_t)(b * 8 + hk) * 128 + dn * 8) * 2048 + t0 + tq * 4;
#pragma unroll
  for (int e = 0; e < 8; e++) {
    short4v pk;
    pk[0] = v0[e]; pk[1] = v1[e]; pk[2] = v2[e]; pk[3] = v3[e];
    *(short4v*)(dst + (size_t)e * 2048) = pk;
  }
}

// ---------------- causal GQA flash attention (swapped-operand, in-reg softmax) ----
// r14 = r13 with the epilogue row-offset bug fixed (qw + qq, was qt*128 + qq).
// K read DIRECTLY from global (L2/L1-hot tile; no Klds) -> LDS 48KB -> 3 blocks/CU
// (launch_bounds(256,3)); 1024 blocks (one q-tile each); descending-work dispatch.
#define ATT_C2 0.1275172707611085f  /* (1/sqrt(128)) * log2(e) */

__global__ __launch_bounds__(256, 3)
void attn_kernel(const ushort* __restrict__ Q, const ushort* __restrict__ Kg,
                 const ushort* __restrict__ Vtg, ushort* __restrict__ O) {
  __shared__ __align__(16) ushort Vlds[2][128 * 64];   // [d][kv], chunk-XOR swizzled
  __shared__ __align__(16) ushort Olds[4][32 * 64];    // per-wave epilogue transpose
  const int t = threadIdx.x, lane = t & 63, w = t >> 6;
  const int bx = blockIdx.x;
  const int hk = bx & 7;            // XCD id under bx%8 round-robin
  const int qh = (bx >> 3) & 3;
  const int b = (bx >> 5) & 1;
  const int qt = 15 - (bx >> 6);    // descending work: longest blocks dispatch first
  const int h = hk * 4 + qh;
  const int ntiles = (qt + 1) * 2;

  const ushort* Qp = Q + ((size_t)(b * 32 + h) * 2048) * 128;
  const ushort* Kp = Kg + ((size_t)(b * 8 + hk) * 2048) * 128;
  const ushort* Vp = Vtg + ((size_t)(b * 8 + hk) * 128) * 2048;

  const int l31 = lane & 31;
  const int hi = lane >> 5;
  const int qw = qt * 128 + w * 32;

  auto stageV = [&](int s) {
    const int kv0 = s * 64;
    ushort* Vd = Vlds[s & 1];
#pragma unroll
    for (int j = 0; j < 4; j++) {
      const int c = j * 256 + t;
      const int d = c >> 3, tc = c & 7;
      gload_lds16(Vp + (size_t)d * 2048 + kv0 + ((tc ^ (d & 7)) << 3),
                  (char*)Vd + c * 16);
    }
  };

  short8 qf[8];          // Q[q=lane&31][ks*16 + hi*8 + e], ks=0..7
  floatx16 o[4];         // O[d][q]: d = dblk*32 + crow(reg,hi), q = lane&31
  float mrun = -3.0e38f, lrun = 0.0f;

#pragma unroll
  for (int ks = 0; ks < 8; ks++)
    qf[ks] = *(const short8*)(Qp + (size_t)(qw + l31) * 128 + ks * 16 + hi * 8);
#pragma unroll
  for (int d = 0; d < 4; d++) o[d] = (floatx16)(0.0f);

  auto compute = [&](int tt, int bsel) {
    const int kv0 = tt * 64;
    if (kv0 > qw + 31) return;
    const ushort* Vd = Vlds[bsel];
    const ushort* Kt = Kp + (size_t)kv0 * 128;
    // ---- QK^T: S[kv][q]; K operand straight from global (L2/L1-hot) ----
    floatx16 s0 = (floatx16)(0.0f), s1 = (floatx16)(0.0f);
    __builtin_amdgcn_s_setprio(1);
#pragma unroll
    for (int ks = 0; ks < 8; ks++) {
      short8 kf0 = *(const short8*)(Kt + (size_t)l31 * 128 + ks * 16 + hi * 8);
      s0 = __builtin_amdgcn_mfma_f32_32x32x16_bf16(kf0, qf[ks], s0, 0, 0, 0);
      short8 kf1 = *(const short8*)(Kt + (size_t)(32 + l31) * 128 + ks * 16 + hi * 8);
      s1 = __builtin_amdgcn_mfma_f32_32x32x16_bf16(kf1, qf[ks], s1, 0, 0, 0);
    }
    __builtin_amdgcn_s_setprio(0);
    const int qg = qw + l31;
    if (kv0 + 63 > qw) {  // boundary tiles only (wave-uniform)
#pragma unroll
      for (int r = 0; r < 16; r++) {
        const int kvr = (r & 3) + 8 * (r >> 2) + 4 * hi;
        if (kv0 + kvr > qg) s0[r] = -3.0e38f;
        if (kv0 + 32 + kvr > qg) s1[r] = -3.0e38f;
      }
    }
    // ---- row max: depth-5 binary tree + one half-wave swap ----
    float mm[16];
#pragma unroll
    for (int r = 0; r < 16; r++) mm[r] = fmaxf(s0[r], s1[r]);
#pragma unroll
    for (int st = 8; st > 0; st >>= 1)
#pragma unroll
      for (int r = 0; r < st; r++) mm[r] = fmaxf(mm[r], mm[r + st]);
    float m1 = fmaxf(mm[0], __shfl_xor(mm[0], 32, 64));
    // ---- defer-max rescale (T13) ----
    if (!__all(m1 - mrun <= 62.73f)) {
      const float mnew = fmaxf(mrun, m1);
      const float alpha = __builtin_amdgcn_exp2f((mrun - mnew) * ATT_C2);
      lrun *= alpha;
#pragma unroll
      for (int d = 0; d < 4; d++)
#pragma unroll
        for (int r = 0; r < 16; r++) o[d][r] *= alpha;
      mrun = mnew;
    }
    // ---- P = 2^((s - m)*c2); sum via depth-5 tree ----
#pragma unroll
    for (int r = 0; r < 16; r++) {
      s0[r] = __builtin_amdgcn_exp2f((s0[r] - mrun) * ATT_C2);
      s1[r] = __builtin_amdgcn_exp2f((s1[r] - mrun) * ATT_C2);
    }
    float sm[16];
#pragma unroll
    for (int r = 0; r < 16; r++) sm[r] = s0[r] + s1[r];
#pragma unroll
    for (int st = 8; st > 0; st >>= 1)
#pragma unroll
      for (int r = 0; r < st; r++) sm[r] += sm[r + st];
    lrun += sm[0] + __shfl_xor(sm[0], 32, 64);
    // ---- P fragments (cvt_pk + permlane32_swap) ----
    short8 pa00 = mkpa8(s0[0], s0[1], s0[2], s0[3], s0[4], s0[5], s0[6], s0[7]);
    short8 pa01 = mkpa8(s0[8], s0[9], s0[10], s0[11], s0[12], s0[13], s0[14], s0[15]);
    short8 pa10 = mkpa8(s1[0], s1[1], s1[2], s1[3], s1[4], s1[5], s1[6], s1[7]);
    short8 pa11 = mkpa8(s1[8], s1[9], s1[10], s1[11], s1[12], s1[13], s1[14], s1[15]);
    // ---- PV: O[d][q] += V^T x P ----
    __builtin_amdgcn_s_setprio(1);
#pragma unroll
    for (int kvb = 0; kvb < 2; kvb++)
#pragma unroll
      for (int sh = 0; sh < 2; sh++) {
        const short8 pa = (kvb == 0) ? (sh == 0 ? pa00 : pa01) : (sh == 0 ? pa10 : pa11);
        const int gc = kvb * 4 + sh * 2 + hi;
#pragma unroll
        for (int d = 0; d < 4; d++) {
          const int vr = d * 32 + l31;
          short8 vf = *(const short8*)((const char*)Vd + vr * 128 + ((gc ^ (vr & 7)) * 16));
          o[d] = __builtin_amdgcn_mfma_f32_32x32x16_bf16(vf, pa, o[d], 0, 0, 0);
        }
      }
    __builtin_amdgcn_s_setprio(0);
  };

  stageV(0);
  __syncthreads();
  for (int i = 0; i < ntiles; ++i) {
    if (i + 1 < ntiles) stageV(i + 1);
    compute(i, i & 1);
    __syncthreads();
  }

  // ---- epilogue: per-wave swizzled LDS transpose -> coalesced stores ----
  {
    const float inv = 1.0f / lrun;
    ushort* Ow = Olds[w];
    const int q = l31;
#pragma unroll
    for (int half = 0; half < 2; half++) {
#pragma unroll
      for (int dd = 0; dd < 2; dd++) {
        const int dblk = half * 2 + dd;
#pragma unroll
        for (int rp = 0; rp < 8; rp++) {
          const int r0 = rp * 2;
          const int d0 = dd * 32 + (r0 & 3) + 8 * (r0 >> 2) + 4 * hi;
          unsigned pk;
          asm("v_cvt_pk_bf16_f32 %0, %1, %2" : "=v"(pk)
              : "v"(o[dblk][r0] * inv), "v"(o[dblk][r0 + 1] * inv));
          *(unsigned*)&Ow[q * 64 + (d0 ^ ((q & 7) << 3))] = pk;
        }
      }
#pragma unroll
      for (int qs = 0; qs < 4; qs++) {
        const int qq = qs * 8 + (lane >> 3);
        const int seg = lane & 7;
        short8 v = *(const short8*)&Ow[qq * 64 + ((seg * 8) ^ ((qq & 7) << 3))];
        *(short8*)&O[(size_t)(b * 2048 + qw + qq) * 4096 + h * 128 + half * 64 + seg * 8] = v;
      }
    }
  }
}

// ---------------- launch ----------------
extern "C" void kernel_launch(void* const* d_in, const int* in_sizes, int n_in,
                              void* d_out, int out_size, void* d_ws, size_t ws_size,
                              hipStream_t stream) {
  const float* x = (const float*)d_in[0];
  const float* rc = (const float*)d_in[1];
  const float* rs = (const float*)d_in[2];
  const float* wqkv = (const float*)d_in[3];
  const float* wproj = (const float*)d_in[4];
  float* out = (float*)d_out;

  // workspace layout (ushort elements)
  ushort* xb = (ushort*)d_ws;            // 16777216  (x bf16; reused late for W_proj bf16)
  ushort* wqkvb = xb + 16777216;         // 25165824
  ushort* qkvb = wqkvb + 25165824;       // 25165824  (qkv; reused for attn out)
  ushort* Qb = qkvb + 25165824;          // 16777216
  ushort* Kb = Qb + 16777216;            // 4194304
  ushort* Vt = Kb + 4194304;             // 4194304   (V^T [B,HK,D,T])
  ushort* wprojb = xb;                   // alias: x dead after GEMM1
  ushort* aob = qkvb;                    // alias: qkv dead after vtrans

  cvt_kernel<<<2048, 256, 0, stream>>>(x, xb, 16777216L);
  cvt_kernel<<<2048, 256, 0, stream>>>(wqkv, wqkvb, 25165824L);
  gemm_pipe<192, 1><<<512, 512, 0, stream>>>(xb, wqkvb, nullptr, qkvb, 4096, 6144, 4096);
  rope_kernel<<<4096, 256, 0, stream>>>(qkvb, rc, rs, Qb, Kb);
  vtrans_kernel<<<512, 256, 0, stream>>>(qkvb, Vt);
  attn_kernel<<<1024, 256, 0, stream>>>(Qb, Kb, Vt, aob);
  cvt_kernel<<<2048, 256, 0, stream>>>(wproj, wprojb, 16777216L);
  gemm_pipe<256, 0><<<256, 512, 0, stream>>>(aob, wprojb, out, nullptr, 4096, 4096, 4096);
}

// Round 15
// 470.291 us; speedup vs baseline: 1.1934x; 1.1934x over previous
//
#include <hip/hip_runtime.h>
#include <hip/hip_bf16.h>

typedef __attribute__((ext_vector_type(8))) short short8;
typedef __attribute__((ext_vector_type(4))) short short4v;
typedef __attribute__((ext_vector_type(4))) float floatx4;
typedef __attribute__((ext_vector_type(16))) float floatx16;
typedef __attribute__((ext_vector_type(4))) unsigned int uintx4;

__device__ __forceinline__ float b2f(ushort u) {
  unsigned x = ((unsigned)u) << 16;
  return __builtin_bit_cast(float, x);
}
__device__ __forceinline__ ushort f2b(float f) {
  unsigned x = __builtin_bit_cast(unsigned, f);
  x += 0x7fffu + ((x >> 16) & 1u);
  return (ushort)(x >> 16);
}

__device__ __forceinline__ void gload_lds16(const void* g, void* l) {
  __builtin_amdgcn_global_load_lds(
      (const __attribute__((address_space(1))) unsigned int*)g,
      (__attribute__((address_space(3))) unsigned int*)l, 16, 0, 0);
}

// P-fragment build (T12): cvt_pk + permlane32_swap (direction verified r10/r11).
__device__ __forceinline__ short8 mkpa8(float p0, float p1, float p2, float p3,
                                        float p4, float p5, float p6, float p7) {
  unsigned a0, a1, b0, b1;
  asm("v_cvt_pk_bf16_f32 %0, %1, %2" : "=v"(a0) : "v"(p0), "v"(p1));
  asm("v_cvt_pk_bf16_f32 %0, %1, %2" : "=v"(a1) : "v"(p2), "v"(p3));
  asm("v_cvt_pk_bf16_f32 %0, %1, %2" : "=v"(b0) : "v"(p4), "v"(p5));
  asm("v_cvt_pk_bf16_f32 %0, %1, %2" : "=v"(b1) : "v"(p6), "v"(p7));
  asm volatile("v_permlane32_swap_b32 %0, %1" : "+v"(a0), "+v"(b0));
  asm volatile("v_permlane32_swap_b32 %0, %1" : "+v"(a1), "+v"(b1));
  uintx4 u;
  u[0] = a0;  // kv 0,1 (lo) / 8,9  (hi)
  u[1] = a1;  // kv 2,3 (lo) / 10,11(hi)
  u[2] = b0;  // kv 4,5 (lo) / 12,13(hi)
  u[3] = b1;  // kv 6,7 (lo) / 14,15(hi)
  return __builtin_bit_cast(short8, u);
}

// ---------------- f32 -> bf16 conversion ----------------
__global__ __launch_bounds__(256) void cvt_kernel(const float* __restrict__ in,
                                                  ushort* __restrict__ out, long n) {
  long i0 = ((long)blockIdx.x * 256 + threadIdx.x) * 4;
  long stride = (long)gridDim.x * 256 * 4;
  for (long i = i0; i < n; i += stride) {
    float4 v = *(const float4*)(in + i);
    ushort4 u;
    u.x = f2b(v.x); u.y = f2b(v.y); u.z = f2b(v.z); u.w = f2b(v.w);
    *(ushort4*)(out + i) = u;
  }
}

// ---------------- pipelined 256xBN GEMM: C[M,N] = A[M,K] * B[N,K]^T ----------------
// r5 structure (proven 186/92 us). Do not re-tinker the wait structure.
template <int BN, int OUTBF16>
__global__ __launch_bounds__(512, 2)
void gemm_pipe(const ushort* __restrict__ A, const ushort* __restrict__ B,
               float* __restrict__ Cf, ushort* __restrict__ Cb,
               int M, int N, int K) {
  constexpr int BNF = BN / 64;
  __shared__ __align__(16) ushort sA[2][256 * 64];
  __shared__ __align__(16) ushort sB[2][BN * 64];
  const int t = threadIdx.x;
  const int lane = t & 63;
  const int L = lane & 15, g = lane >> 4;
  const int w = t >> 6;
  const int wr = w >> 2, wc = w & 3;
  const int ntn = N / BN;
  const int nwg = gridDim.x;
  const int wg = blockIdx.x;
  const int swz = (wg & 7) * (nwg >> 3) + (wg >> 3);
  const int m0 = (swz / ntn) << 8;
  const int n0 = (swz % ntn) * BN;

  floatx4 acc[8][BNF];
#pragma unroll
  for (int i = 0; i < 8; i++)
#pragma unroll
    for (int j = 0; j < BNF; j++) acc[i][j] = (floatx4)(0.0f);

  const ushort* Ab = A + (size_t)m0 * K;
  const ushort* Bb = B + (size_t)n0 * K;

  auto stage_tile = [&](const ushort* Ag, const ushort* Bg, int buf) {
#pragma unroll
    for (int j = 0; j < 4; j++) {
      const int c = j * 512 + t;
      const int row = c >> 3, ch = c & 7;
      const int kc = ch ^ (row & 7);
      gload_lds16(Ag + (size_t)row * K + kc * 8, (char*)&sA[buf][0] + c * 16);
    }
#pragma unroll
    for (int j = 0; j < BN / 64; j++) {
      const int c = j * 512 + t;
      const int row = c >> 3, ch = c & 7;
      const int kc = ch ^ (row & 7);
      gload_lds16(Bg + (size_t)row * K + kc * 8, (char*)&sB[buf][0] + c * 16);
    }
  };
  auto rdA = [&](int buf, int mh, int kc16, short8* dst) {
#pragma unroll
    for (int i = 0; i < 4; i++) {
      const int row = wr * 128 + mh * 64 + i * 16 + L;
      const int ch = (kc16 * 4 + g) ^ (row & 7);
      dst[i] = *(const short8*)((const char*)&sA[buf][0] + row * 128 + ch * 16);
    }
  };
  auto rdB = [&](int buf, int kc16, short8* dst) {
#pragma unroll
    for (int i = 0; i < BNF; i++) {
      const int row = wc * (BN / 4) + i * 16 + L;
      const int ch = (kc16 * 4 + g) ^ (row & 7);
      dst[i] = *(const short8*)((const char*)&sB[buf][0] + row * 128 + ch * 16);
    }
  };

  short8 a0[4], a1[4], b0[BNF], b1[BNF];

  auto mfmaN = [&](short8* af, short8* bf, int accbase, int cnt) {
    __builtin_amdgcn_s_setprio(1);
    for (int i = 0; i < cnt; i++)
#pragma unroll
      for (int nf = 0; nf < BNF; nf++)
        acc[accbase + i][nf] =
            __builtin_amdgcn_mfma_f32_16x16x32_bf16(af[i], bf[nf], acc[accbase + i][nf], 0, 0, 0);
    __builtin_amdgcn_s_setprio(0);
  };

  const int NT = K >> 6;
  stage_tile(Ab, Bb, 0);
  __syncthreads();
  rdA(0, 0, 0, a0);
  rdB(0, 0, b0);

  for (int T = 0; T < NT; ++T) {
    const int p = T & 1, q = p ^ 1;
    const bool more = (T + 1 < NT);
    if (more) stage_tile(Ab + (T + 1) * 64, Bb + (T + 1) * 64, q);
    rdA(p, 1, 0, a1);
    mfmaN(a0, b0, 0, 4);
    rdA(p, 0, 1, a0);
    rdB(p, 1, b1);
    mfmaN(a1, b0, 4, 4);
    rdA(p, 1, 1, a1);
    mfmaN(a0, b1, 0, 4);
    mfmaN(a1, b1, 4, 2);
    __syncthreads();
    if (more) {
      rdA(q, 0, 0, a0);
      rdB(q, 0, b0);
    }
    mfmaN(a1 + 2, b1, 6, 2);
  }

#pragma unroll
  for (int mf = 0; mf < 8; mf++)
#pragma unroll
    for (int nf = 0; nf < BNF; nf++)
#pragma unroll
      for (int r = 0; r < 4; r++) {
        const int row = m0 + wr * 128 + mf * 16 + g * 4 + r;
        const int col = n0 + wc * (BN / 4) + nf * 16 + L;
        if (OUTBF16)
          Cb[(size_t)row * N + col] = f2b(acc[mf][nf][r]);
        else
          Cf[(size_t)row * N + col] = acc[mf][nf][r];
      }
}

// ---------------- RoPE + split qkv -> Q[B,H,T,D], K[B,HK,T,D] ----------------
__global__ __launch_bounds__(256)
void rope_kernel(const ushort* __restrict__ qkv, const float* __restrict__ cosp,
                 const float* __restrict__ sinp, ushort* __restrict__ Qo,
                 ushort* __restrict__ Ko) {
  const int row = blockIdx.x;            // b*2048 + t
  const int b = row >> 11, tt = row & 2047;
  const int i = threadIdx.x;
  const ushort* qr = qkv + (size_t)row * 6144;

  const int jb = (i & 7) * 8;
  float cs[8], sn[8];
  *(float4*)&cs[0] = *(const float4*)(cosp + tt * 128 + jb);
  *(float4*)&cs[4] = *(const float4*)(cosp + tt * 128 + jb + 4);
  *(float4*)&sn[0] = *(const float4*)(sinp + tt * 128 + jb);
  *(float4*)&sn[4] = *(const float4*)(sinp + tt * 128 + jb + 4);

  {
    const int hh = i >> 3;
    short8 lo = *(const short8*)(qr + hh * 128 + jb);
    short8 hi = *(const short8*)(qr + hh * 128 + 64 + jb);
    short8 olo, ohi;
#pragma unroll
    for (int e = 0; e < 8; e++) {
      float fl = b2f((ushort)lo[e]), fh = b2f((ushort)hi[e]);
      olo[e] = (short)f2b(fl * cs[e] - fh * sn[e]);
      ohi[e] = (short)f2b(fh * cs[e] + fl * sn[e]);
    }
    ushort* dst = Qo + ((size_t)(b * 32 + hh) * 2048 + tt) * 128 + jb;
    *(short8*)dst = olo;
    *(short8*)(dst + 64) = ohi;
  }
  if (i < 64) {
    const int hkk = i >> 3;
    short8 lo = *(const short8*)(qr + 4096 + hkk * 128 + jb);
    short8 hi = *(const short8*)(qr + 4096 + hkk * 128 + 64 + jb);
    short8 olo, ohi;
#pragma unroll
    for (int e = 0; e < 8; e++) {
      float fl = b2f((ushort)lo[e]), fh = b2f((ushort)hi[e]);
      olo[e] = (short)f2b(fl * cs[e] - fh * sn[e]);
      ohi[e] = (short)f2b(fh * cs[e] + fl * sn[e]);
    }
    ushort* dst = Ko + ((size_t)(b * 8 + hkk) * 2048 + tt) * 128 + jb;
    *(short8*)dst = olo;
    *(short8*)(dst + 64) = ohi;
  }
}

// ---------------- V transpose: qkv V slice -> Vt[B,HK,D,T] ----------------
__global__ __launch_bounds__(256)
void vtrans_kernel(const ushort* __restrict__ qkv, ushort* __restrict__ Vt) {
  const int bx = blockIdx.x;
  const int t0 = (bx & 31) * 64;
  const int hk = (bx >> 5) & 7;
  const int b = bx >> 8;
  const int i = threadIdx.x;
  const int tq = i & 15;
  const int dn = i >> 4;
  const ushort* src = qkv + ((size_t)(b * 2048 + t0 + tq * 4)) * 6144 + 5120 + hk * 128 + dn * 8;
  short8 v0 = *(const short8*)(src);
  short8 v1 = *(const short8*)(src + 6144);
  short8 v2 = *(const short8*)(src + 12288);
  short8 v3 = *(const short8*)(src + 18432);
  ushort* dst = Vt + ((size_t)(b * 8 + hk) * 128 + dn * 8) * 2048 + t0 + tq * 4;
#pragma unroll
  for (int e = 0; e < 8; e++) {
    short4v pk;
    pk[0] = v0[e]; pk[1] = v1[e]; pk[2] = v2[e]; pk[3] = v3[e];
    *(short4v*)(dst + (size_t)e * 2048) = pk;
  }
}

// ---------------- causal GQA flash attention (swapped-operand, in-reg softmax) ----
// 512 blocks, XCD decode hk=bx&7. Per wave 32 q rows. QK^T = mfma32x32(K,Q) ->
// S[kv][q] with q=lane&31: softmax state is per-lane scalar; row-reduce = in-lane
// tree + one shfl_xor(32). P->bf16 via cvt_pk + permlane32_swap (no LDS round-trip).
// PV = mfma32x32(V^T, P) -> O[d][q] keeps q=lane&31 (scalar rescale). Defer-max
// rescale (T13). setprio around MFMA clusters (T5). Epilogue: per-wave swizzled
// LDS transpose -> coalesced stores. [r15 = r11 verbatim: best measured 470us;
// r12 chain-split/trees = noise; r13/r14 K-from-global = regression (MFMA
// operands must come from LDS/registers -- access pattern, not hit rate).]
#define ATT_C2 0.1275172707611085f  /* (1/sqrt(128)) * log2(e) */

__global__ __launch_bounds__(256, 2)
void attn_kernel(const ushort* __restrict__ Q, const ushort* __restrict__ Kg,
                 const ushort* __restrict__ Vtg, ushort* __restrict__ O) {
  __shared__ __align__(16) ushort Klds[2][64 * 128];   // [kv][d], chunk-XOR swizzled
  __shared__ __align__(16) ushort Vlds[2][128 * 64];   // [d][kv], chunk-XOR swizzled
  __shared__ __align__(16) ushort Olds[4][32 * 64];    // per-wave epilogue transpose
  const int t = threadIdx.x, lane = t & 63, w = t >> 6;
  const int bx = blockIdx.x;
  const int hk = bx & 7;            // XCD id under bx%8 round-robin
  const int qh = (bx >> 3) & 3;
  const int b = (bx >> 5) & 1;
  const int pair = bx >> 6;
  const int h = hk * 4 + qh;
  const int qtA = pair, qtB = 15 - pair;
  const int nA = (qtA + 1) * 2, nB = (qtB + 1) * 2;
  const int total = nA + nB;  // 34

  const ushort* Qp = Q + ((size_t)(b * 32 + h) * 2048) * 128;
  const ushort* Kp = Kg + ((size_t)(b * 8 + hk) * 2048) * 128;
  const ushort* Vp = Vtg + ((size_t)(b * 8 + hk) * 128) * 2048;

  const int l31 = lane & 31;
  const int hi = lane >> 5;

  auto stage = [&](int s) {
    const int tt = (s < nA) ? s : s - nA;
    const int kv0 = tt * 64;
    ushort* Kd = Klds[s & 1];
    ushort* Vd = Vlds[s & 1];
#pragma unroll
    for (int j = 0; j < 4; j++) {
      const int c = j * 256 + t;
      const int krow = c >> 4, kcol = c & 15;
      gload_lds16(Kp + (size_t)(kv0 + krow) * 128 + ((kcol ^ (krow & 15)) << 3),
                  (char*)Kd + c * 16);
    }
#pragma unroll
    for (int j = 0; j < 4; j++) {
      const int c = j * 256 + t;
      const int d = c >> 3, tc = c & 7;
      gload_lds16(Vp + (size_t)d * 2048 + kv0 + ((tc ^ (d & 7)) << 3),
                  (char*)Vd + c * 16);
    }
  };

  short8 qf[8];          // Q[q=lane&31][ks*16 + hi*8 + e], ks=0..7
  floatx16 o[4];         // O[d][q]: d = dblk*32 + crow(reg,hi), q = lane&31
  float mrun, lrun;

  auto init_pass = [&](int qw_) {
#pragma unroll
    for (int ks = 0; ks < 8; ks++)
      qf[ks] = *(const short8*)(Qp + (size_t)(qw_ + l31) * 128 + ks * 16 + hi * 8);
#pragma unroll
    for (int d = 0; d < 4; d++) o[d] = (floatx16)(0.0f);
    mrun = -3.0e38f;
    lrun = 0.0f;
  };

  auto compute = [&](int tt, int bsel, int qw_) {
    const int kv0 = tt * 64;
    if (kv0 > qw_ + 31) return;
    const ushort* Kd = Klds[bsel];
    const ushort* Vd = Vlds[bsel];
    // ---- QK^T: S[kv][q], two 32-kv blocks ----
    floatx16 s0 = (floatx16)(0.0f), s1 = (floatx16)(0.0f);
    __builtin_amdgcn_s_setprio(1);
#pragma unroll
    for (int ks = 0; ks < 8; ks++) {
      const int gc = ks * 2 + hi;
      const int r0 = l31;
      short8 kf0 = *(const short8*)((const char*)Kd + r0 * 256 + ((gc ^ (r0 & 15)) * 16));
      s0 = __builtin_amdgcn_mfma_f32_32x32x16_bf16(kf0, qf[ks], s0, 0, 0, 0);
      const int r1 = 32 + l31;
      short8 kf1 = *(const short8*)((const char*)Kd + r1 * 256 + ((gc ^ (r1 & 15)) * 16));
      s1 = __builtin_amdgcn_mfma_f32_32x32x16_bf16(kf1, qf[ks], s1, 0, 0, 0);
    }
    __builtin_amdgcn_s_setprio(0);
    const int qg = qw_ + l31;
    if (kv0 + 63 > qw_) {  // boundary tiles only (wave-uniform)
#pragma unroll
      for (int r = 0; r < 16; r++) {
        const int kvr = (r & 3) + 8 * (r >> 2) + 4 * hi;
        if (kv0 + kvr > qg) s0[r] = -3.0e38f;
        if (kv0 + 32 + kvr > qg) s1[r] = -3.0e38f;
      }
    }
    // ---- row max (in-lane tree + one swap) ----
    float m1 = fmaxf(s0[0], s0[1]);
#pragma unroll
    for (int r = 2; r < 16; r++) m1 = fmaxf(m1, s0[r]);
#pragma unroll
    for (int r = 0; r < 16; r++) m1 = fmaxf(m1, s1[r]);
    m1 = fmaxf(m1, __shfl_xor(m1, 32, 64));
    // ---- defer-max rescale (T13): THR = 8 / C2 in raw-score units ----
    if (!__all(m1 - mrun <= 62.73f)) {
      const float mnew = fmaxf(mrun, m1);
      const float alpha = __builtin_amdgcn_exp2f((mrun - mnew) * ATT_C2);
      lrun *= alpha;
#pragma unroll
      for (int d = 0; d < 4; d++)
#pragma unroll
        for (int r = 0; r < 16; r++) o[d][r] *= alpha;
      mrun = mnew;
    }
    // ---- P = 2^((s - m)*c2), row sum ----
    float ls = 0.0f;
#pragma unroll
    for (int r = 0; r < 16; r++) {
      float p = __builtin_amdgcn_exp2f((s0[r] - mrun) * ATT_C2);
      s0[r] = p; ls += p;
    }
#pragma unroll
    for (int r = 0; r < 16; r++) {
      float p = __builtin_amdgcn_exp2f((s1[r] - mrun) * ATT_C2);
      s1[r] = p; ls += p;
    }
    ls += __shfl_xor(ls, 32, 64);
    lrun += ls;
    // ---- P fragments (cvt_pk + permlane32_swap) ----
    short8 pa00 = mkpa8(s0[0], s0[1], s0[2], s0[3], s0[4], s0[5], s0[6], s0[7]);
    short8 pa01 = mkpa8(s0[8], s0[9], s0[10], s0[11], s0[12], s0[13], s0[14], s0[15]);
    short8 pa10 = mkpa8(s1[0], s1[1], s1[2], s1[3], s1[4], s1[5], s1[6], s1[7]);
    short8 pa11 = mkpa8(s1[8], s1[9], s1[10], s1[11], s1[12], s1[13], s1[14], s1[15]);
    // ---- PV: O[d][q] += V^T x P ----
    __builtin_amdgcn_s_setprio(1);
#pragma unroll
    for (int kvb = 0; kvb < 2; kvb++)
#pragma unroll
      for (int sh = 0; sh < 2; sh++) {
        const short8 pa = (kvb == 0) ? (sh == 0 ? pa00 : pa01) : (sh == 0 ? pa10 : pa11);
        const int gc = kvb * 4 + sh * 2 + hi;
#pragma unroll
        for (int d = 0; d < 4; d++) {
          const int vr = d * 32 + l31;
          short8 vf = *(const short8*)((const char*)Vd + vr * 128 + ((gc ^ (vr & 7)) * 16));
          o[d] = __builtin_amdgcn_mfma_f32_32x32x16_bf16(vf, pa, o[d], 0, 0, 0);
        }
      }
    __builtin_amdgcn_s_setprio(0);
  };

  auto epilogue = [&](int qw_) {
    const float inv = 1.0f / lrun;
    ushort* Ow = Olds[w];
    const int q = l31;
#pragma unroll
    for (int half = 0; half < 2; half++) {
      // write 64 d-values (2 dblks) for own q, swizzled [q][d ^ ((q&7)<<3)]
#pragma unroll
      for (int dd = 0; dd < 2; dd++) {
        const int dblk = half * 2 + dd;
#pragma unroll
        for (int rp = 0; rp < 8; rp++) {
          const int r0 = rp * 2;
          const int d0 = dd * 32 + (r0 & 3) + 8 * (r0 >> 2) + 4 * hi;
          unsigned pk;
          asm("v_cvt_pk_bf16_f32 %0, %1, %2" : "=v"(pk)
              : "v"(o[dblk][r0] * inv), "v"(o[dblk][r0 + 1] * inv));
          *(unsigned*)&Ow[q * 64 + (d0 ^ ((q & 7) << 3))] = pk;
        }
      }
      // read out rows, coalesced global store (8 q-rows x 8 segs x 16B per instr)
#pragma unroll
      for (int qs = 0; qs < 4; qs++) {
        const int qq = qs * 8 + (lane >> 3);
        const int seg = lane & 7;
        short8 v = *(const short8*)&Ow[qq * 64 + ((seg * 8) ^ ((qq & 7) << 3))];
        *(short8*)&O[(size_t)(b * 2048 + qw_ + qq) * 4096 + h * 128 + half * 64 + seg * 8] = v;
      }
    }
  };

  int s = 0;
  stage(0);
  __syncthreads();

  int qw = qtA * 128 + w * 32;
  init_pass(qw);
  for (int i = 0; i < nA; ++i, ++s) {
    if (s + 1 < total) stage(s + 1);
    compute(i, s & 1, qw);
    __syncthreads();
  }
  epilogue(qw);

  qw = qtB * 128 + w * 32;
  init_pass(qw);
  for (int i = 0; i < nB; ++i, ++s) {
    if (s + 1 < total) stage(s + 1);
    compute(i, s & 1, qw);
    __syncthreads();
  }
  epilogue(qw);
}

// ---------------- launch ----------------
extern "C" void kernel_launch(void* const* d_in, const int* in_sizes, int n_in,
                              void* d_out, int out_size, void* d_ws, size_t ws_size,
                              hipStream_t stream) {
  const float* x = (const float*)d_in[0];
  const float* rc = (const float*)d_in[1];
  const float* rs = (const float*)d_in[2];
  const float* wqkv = (const float*)d_in[3];
  const float* wproj = (const float*)d_in[4];
  float* out = (float*)d_out;

  // workspace layout (ushort elements)
  ushort* xb = (ushort*)d_ws;            // 16777216  (x bf16; reused late for W_proj bf16)
  ushort* wqkvb = xb + 16777216;         // 25165824
  ushort* qkvb = wqkvb + 25165824;       // 25165824  (qkv; reused for attn out)
  ushort* Qb = qkvb + 25165824;          // 16777216
  ushort* Kb = Qb + 16777216;            // 4194304
  ushort* Vt = Kb + 4194304;             // 4194304   (V^T [B,HK,D,T])
  ushort* wprojb = xb;                   // alias: x dead after GEMM1
  ushort* aob = qkvb;                    // alias: qkv dead after vtrans

  cvt_kernel<<<2048, 256, 0, stream>>>(x, xb, 16777216L);
  cvt_kernel<<<2048, 256, 0, stream>>>(wqkv, wqkvb, 25165824L);
  gemm_pipe<192, 1><<<512, 512, 0, stream>>>(xb, wqkvb, nullptr, qkvb, 4096, 6144, 4096);
  rope_kernel<<<4096, 256, 0, stream>>>(qkvb, rc, rs, Qb, Kb);
  vtrans_kernel<<<512, 256, 0, stream>>>(qkvb, Vt);
  attn_kernel<<<512, 256, 0, stream>>>(Qb, Kb, Vt, aob);
  cvt_kernel<<<2048, 256, 0, stream>>>(wproj, wprojb, 16777216L);
  gemm_pipe<256, 0><<<256, 512, 0, stream>>>(aob, wprojb, out, nullptr, 4096, 4096, 4096);
}